// Round 1
// baseline (295.866 us; speedup 1.0000x reference)
//
#include <hip/hip_runtime.h>
#include <cmath>

#define HH 1024
#define WW 1024
#define KS 51
#define RAD 25
#define PLANE (HH * WW)

struct GaussW { float w[KS]; };

// ---------------------------------------------------------------------------
// Horizontal 51-tap blur. Thread = 16 consecutive outputs; 18 float4 global
// loads feed 816 FMAs, input-stationary: each loaded float4 is consumed
// immediately (acc[16] + v live -> low VGPR -> high occupancy + load ILP).
// Weights by value -> SGPRs -> v_fmac s,v. Block = 4 rows x 64 threads;
// wave == one row so edge divergence stays in 2 lanes.
// ---------------------------------------------------------------------------
__global__ __launch_bounds__(256) void hblur_kernel(const float* __restrict__ x,
                                                    float* __restrict__ tmp,
                                                    GaussW gw)
{
    const int t    = threadIdx.x;
    const int lane = t & 63;
    const int r    = t >> 6;                       // wave-uniform
    const long long row = (long long)blockIdx.x * 4 + r;
    const float* src = x + row * WW;
    const int j0 = lane * 16;                      // outputs j0..j0+15

    float acc[16];
    #pragma unroll
    for (int d = 0; d < 16; d++) acc[d] = 0.f;

    // window covers cols j0-28 .. j0+43 (need j0-25 .. j0+40); 18 aligned float4
    #pragma unroll
    for (int i = 0; i < 18; i++) {
        const int b = j0 - 28 + i * 4;
        float4 v;
        if (b >= 0 && b + 3 < WW) {
            v = *(const float4*)(src + b);
        } else {                                   // only lane 0 / lane 63
            float tv[4];
            #pragma unroll
            for (int q = 0; q < 4; q++) {
                const int c = b + q;
                tv[q] = (c >= 0 && c < WW) ? src[c] : 0.f;
            }
            v = make_float4(tv[0], tv[1], tv[2], tv[3]);
        }
        const float vq[4] = {v.x, v.y, v.z, v.w};
        #pragma unroll
        for (int q = 0; q < 4; q++) {
            const int wi = i * 4 + q;              // window index: col j0-28+wi
            #pragma unroll
            for (int d = 0; d < 16; d++) {
                const int k = wi - 3 - d;          // compile-time tap index
                if (k >= 0 && k < KS)
                    acc[d] = fmaf(gw.w[k], vq[q], acc[d]);
            }
        }
    }

    float* dst = tmp + row * WW;
    #pragma unroll
    for (int g = 0; g < 4; g++)
        *(float4*)(dst + j0 + g * 4) =
            make_float4(acc[g*4], acc[g*4+1], acc[g*4+2], acc[g*4+3]);
}

// ---------------------------------------------------------------------------
// Vertical 51-tap blur + screen blend + clamp. Thread = 2 consecutive cols
// (float2) x 16 rows: acc = 32 VGPRs (R2's float4 x 16 was ~VGPR-bound and
// regressed). 66 coalesced float2 loads (512 B/instr) -> 1632 FMAs,
// input-stationary. Row guards wave-uniform. tile_y inner so vertically-
// adjacent blocks share halo rows in L2.
// ---------------------------------------------------------------------------
__global__ __launch_bounds__(256) void vblend_kernel(const float* __restrict__ tmp,
                                                     const float* __restrict__ x,
                                                     float* __restrict__ out,
                                                     GaussW gw,
                                                     const float* __restrict__ amountp)
{
    const int t      = threadIdx.x;
    const int bid    = blockIdx.x;
    const int plane  = bid >> 7;            // 128 tiles per plane
    const int rem    = bid & 127;
    const int tile_x = rem >> 4;            // 8 col-tiles of 128
    const int tile_y = rem & 15;            // inner -> vertical L2 reuse
    const int c0     = tile_x * 128 + (t & 63) * 2;
    const int r0     = tile_y * 64 + (t >> 6) * 16;   // wave-uniform row group

    const float* tp = tmp + (size_t)plane * PLANE + c0;

    float2 acc[16];
    #pragma unroll
    for (int j = 0; j < 16; j++) acc[j] = make_float2(0.f, 0.f);

    #pragma unroll
    for (int i = 0; i < 66; i++) {
        const int ri = r0 - RAD + i;
        float2 v = make_float2(0.f, 0.f);
        if (ri >= 0 && ri < HH) v = *(const float2*)(tp + (size_t)ri * WW);
        #pragma unroll
        for (int j = 0; j < 16; j++) {
            const int k = i - j;                  // compile-time tap index
            if (k >= 0 && k < KS) {
                const float wk = gw.w[k];
                acc[j].x = fmaf(wk, v.x, acc[j].x);
                acc[j].y = fmaf(wk, v.y, acc[j].y);
            }
        }
    }

    const float p = amountp[0];
    const float s = 1.2f * (0.4f / (1.f + expf(-p)));   // 1.2 * amount

    const float* xp = x   + (size_t)plane * PLANE + c0;
    float*       op = out + (size_t)plane * PLANE + c0;
    #pragma unroll
    for (int j = 0; j < 16; j++) {
        const float2 xv = *(const float2*)(xp + (size_t)(r0 + j) * WW);
        float2 res;
        res.x = 1.f - (1.f - xv.x) * (1.f - s * acc[j].x);
        res.y = 1.f - (1.f - xv.y) * (1.f - s * acc[j].y);
        res.x = fminf(fmaxf(res.x, 0.f), 1.f);
        res.y = fminf(fmaxf(res.y, 0.f), 1.f);
        *(float2*)(op + (size_t)(r0 + j) * WW) = res;
    }
}

// ---------------------------------------------------------------------------
extern "C" void kernel_launch(void* const* d_in, const int* in_sizes, int n_in,
                              void* d_out, int out_size, void* d_ws, size_t ws_size,
                              hipStream_t stream)
{
    const float* x       = (const float*)d_in[0];
    const float* amountp = (const float*)d_in[1];
    float* out = (float*)d_out;
    float* tmp = (float*)d_ws;

    // Gaussian weights (sigma=15, size 51), normalized — identical every call.
    GaussW gw;
    {
        double e[KS], sum = 0.0;
        for (int i = 0; i < KS; i++) {
            const double d = (double)(i - RAD);
            e[i] = exp(-d * d / (2.0 * 15.0 * 15.0));
            sum += e[i];
        }
        for (int i = 0; i < KS; i++) gw.w[i] = (float)(e[i] / sum);
    }

    const int total_planes = in_sizes[0] / PLANE;      // 24
    const size_t plane_bytes = (size_t)PLANE * sizeof(float);
    int P = (int)(ws_size / plane_bytes);
    if (P < 1) P = 1;
    if (P > total_planes) P = total_planes;

    for (int p0 = 0; p0 < total_planes; p0 += P) {
        const int pc = (total_planes - p0 < P) ? (total_planes - p0) : P;
        hblur_kernel<<<pc * 256, 256, 0, stream>>>(x + (size_t)p0 * PLANE, tmp, gw);
        vblend_kernel<<<pc * 128, 256, 0, stream>>>(tmp,
                                                    x + (size_t)p0 * PLANE,
                                                    out + (size_t)p0 * PLANE,
                                                    gw, amountp);
    }
}

// Round 2
// 291.263 us; speedup vs baseline: 1.0158x; 1.0158x over previous
//
#include <hip/hip_runtime.h>
#include <cmath>

#define HH 1024
#define WW 1024
#define KS 51
#define RAD 25
#define PLANE (HH * WW)

struct GaussW { float w[KS]; };

// ---------------------------------------------------------------------------
// Horizontal 51-tap blur. Thread = 16 consecutive outputs.
// R1 change: loads are UNCONDITIONAL (clamped base + zero-select on the value)
// and issued in an explicit phase before the FMA block, so the compiler can
// keep all 18 float4 loads in flight (was: per-iteration branchy load ->
// exposed latency -> VALUBusy 28%). b is always a multiple of 4, so every
// float4 window chunk is fully in-bounds or fully out -> select, not gather.
// ---------------------------------------------------------------------------
__global__ __launch_bounds__(256) void hblur_kernel(const float* __restrict__ x,
                                                    float* __restrict__ tmp,
                                                    GaussW gw)
{
    const int t    = threadIdx.x;
    const int lane = t & 63;
    const int r    = t >> 6;                       // wave-uniform
    const long long row = (long long)blockIdx.x * 4 + r;
    const float* src = x + row * WW;
    const int j0 = lane * 16;                      // outputs j0..j0+15

    // Phase 1: 18 independent, unconditional float4 loads covering
    // cols j0-28 .. j0+43 (window needs j0-25 .. j0+40).
    float4 v[18];
    #pragma unroll
    for (int i = 0; i < 18; i++) {
        const int b = j0 - 28 + i * 4;             // multiple of 4
        const bool in = ((unsigned)b < (unsigned)WW);  // fully-in (b<=1020) or fully-out
        const int bc = in ? b : 0;
        float4 vv = *(const float4*)(src + bc);
        if (!in) vv = make_float4(0.f, 0.f, 0.f, 0.f);
        v[i] = vv;
    }

    // Phase 2: 816 FMAs, input-stationary over the preloaded window.
    float acc[16];
    #pragma unroll
    for (int d = 0; d < 16; d++) acc[d] = 0.f;

    #pragma unroll
    for (int i = 0; i < 18; i++) {
        const float vq[4] = {v[i].x, v[i].y, v[i].z, v[i].w};
        #pragma unroll
        for (int q = 0; q < 4; q++) {
            const int wi = i * 4 + q;              // window index: col j0-28+wi
            #pragma unroll
            for (int d = 0; d < 16; d++) {
                const int k = wi - 3 - d;          // compile-time tap index
                if (k >= 0 && k < KS)
                    acc[d] = fmaf(gw.w[k], vq[q], acc[d]);
            }
        }
    }

    float* dst = tmp + row * WW;
    #pragma unroll
    for (int g = 0; g < 4; g++)
        *(float4*)(dst + j0 + g * 4) =
            make_float4(acc[g*4], acc[g*4+1], acc[g*4+2], acc[g*4+3]);
}

// ---------------------------------------------------------------------------
// Vertical blur body, templated on INTERIOR so the 14/16 interior tiles get a
// completely branch-free loop of 66 unconditional float2 loads (hoistable /
// software-pipelinable by the scheduler). Edge tiles use clamped-row loads
// with a zero-select — still unconditional loads.
// ---------------------------------------------------------------------------
template <bool INTERIOR>
__device__ __forceinline__ void vblur_accum(const float* __restrict__ tp,
                                            int r0, const GaussW& gw,
                                            float2 (&acc)[16])
{
    #pragma unroll
    for (int i = 0; i < 66; i++) {
        const int ri = r0 - RAD + i;
        float2 v;
        if (INTERIOR) {
            v = *(const float2*)(tp + (size_t)ri * WW);
        } else {
            const int ric = min(max(ri, 0), HH - 1);
            v = *(const float2*)(tp + (size_t)ric * WW);
            if ((unsigned)ri >= (unsigned)HH) v = make_float2(0.f, 0.f);
        }
        #pragma unroll
        for (int j = 0; j < 16; j++) {
            const int k = i - j;                  // compile-time tap index
            if (k >= 0 && k < KS) {
                const float wk = gw.w[k];
                acc[j].x = fmaf(wk, v.x, acc[j].x);
                acc[j].y = fmaf(wk, v.y, acc[j].y);
            }
        }
    }
}

// ---------------------------------------------------------------------------
// Vertical 51-tap blur + screen blend + clamp. Thread = 2 consecutive cols
// (float2) x 16 rows. Block-uniform interior/edge split hoists all bounds
// logic out of the load loop. tile_y inner so vertically-adjacent blocks
// share halo rows in L2.
// ---------------------------------------------------------------------------
__global__ __launch_bounds__(256) void vblend_kernel(const float* __restrict__ tmp,
                                                     const float* __restrict__ x,
                                                     float* __restrict__ out,
                                                     GaussW gw,
                                                     const float* __restrict__ amountp)
{
    const int t      = threadIdx.x;
    const int bid    = blockIdx.x;
    const int plane  = bid >> 7;            // 128 tiles per plane
    const int rem    = bid & 127;
    const int tile_x = rem >> 4;            // 8 col-tiles of 128
    const int tile_y = rem & 15;            // inner -> vertical L2 reuse
    const int c0     = tile_x * 128 + (t & 63) * 2;
    const int r0     = tile_y * 64 + (t >> 6) * 16;   // wave-uniform row group

    const float* tp = tmp + (size_t)plane * PLANE + c0;

    float2 acc[16];
    #pragma unroll
    for (int j = 0; j < 16; j++) acc[j] = make_float2(0.f, 0.f);

    // tile_y 1..14: rows r0-25 .. r0+40 all within [0,1024) -> branch-free.
    if (tile_y > 0 && tile_y < 15)
        vblur_accum<true>(tp, r0, gw, acc);
    else
        vblur_accum<false>(tp, r0, gw, acc);

    const float p = amountp[0];
    const float s = 1.2f * (0.4f / (1.f + expf(-p)));   // 1.2 * amount

    const float* xp = x   + (size_t)plane * PLANE + c0;
    float*       op = out + (size_t)plane * PLANE + c0;
    #pragma unroll
    for (int j = 0; j < 16; j++) {
        const float2 xv = *(const float2*)(xp + (size_t)(r0 + j) * WW);
        float2 res;
        res.x = 1.f - (1.f - xv.x) * (1.f - s * acc[j].x);
        res.y = 1.f - (1.f - xv.y) * (1.f - s * acc[j].y);
        res.x = fminf(fmaxf(res.x, 0.f), 1.f);
        res.y = fminf(fmaxf(res.y, 0.f), 1.f);
        *(float2*)(op + (size_t)(r0 + j) * WW) = res;
    }
}

// ---------------------------------------------------------------------------
extern "C" void kernel_launch(void* const* d_in, const int* in_sizes, int n_in,
                              void* d_out, int out_size, void* d_ws, size_t ws_size,
                              hipStream_t stream)
{
    const float* x       = (const float*)d_in[0];
    const float* amountp = (const float*)d_in[1];
    float* out = (float*)d_out;
    float* tmp = (float*)d_ws;

    // Gaussian weights (sigma=15, size 51), normalized — identical every call.
    GaussW gw;
    {
        double e[KS], sum = 0.0;
        for (int i = 0; i < KS; i++) {
            const double d = (double)(i - RAD);
            e[i] = exp(-d * d / (2.0 * 15.0 * 15.0));
            sum += e[i];
        }
        for (int i = 0; i < KS; i++) gw.w[i] = (float)(e[i] / sum);
    }

    const int total_planes = in_sizes[0] / PLANE;      // 24
    const size_t plane_bytes = (size_t)PLANE * sizeof(float);
    int P = (int)(ws_size / plane_bytes);
    if (P < 1) P = 1;
    if (P > total_planes) P = total_planes;

    for (int p0 = 0; p0 < total_planes; p0 += P) {
        const int pc = (total_planes - p0 < P) ? (total_planes - p0) : P;
        hblur_kernel<<<pc * 256, 256, 0, stream>>>(x + (size_t)p0 * PLANE, tmp, gw);
        vblend_kernel<<<pc * 128, 256, 0, stream>>>(tmp,
                                                    x + (size_t)p0 * PLANE,
                                                    out + (size_t)p0 * PLANE,
                                                    gw, amountp);
    }
}

// Round 3
// 241.197 us; speedup vs baseline: 1.2267x; 1.2076x over previous
//
#include <hip/hip_runtime.h>
#include <cmath>

#define HH 1024
#define WW 1024
#define KS 51
#define RAD 25
#define PLANE (HH * WW)

struct GaussW { float w[KS]; };

// ---------------------------------------------------------------------------
// Horizontal 51-tap blur, wave-per-row, LDS-staged.
// R2 change: the old layout (lane owns 16 contiguous cols) gave every global
// load/store a 64 B inter-lane stride -> each wave instruction fragmented into
// ~64 L1 line-transactions (4x the request-pipe cost) -> TA-bound at 107 us,
// VALUBusy 22%. Now: a row (1024 floats) == 64 lanes x 16, so the wave loads
// the row COALESCED (4x float4/lane, 1 KB/instr), stages it in a private 4 KB
// LDS slice, each lane reads its 18-float4 window from LDS, and results
// round-trip through LDS so stores are coalesced too.
// XOR swizzle b ^= ((b>>7)&7)<<4 makes BOTH phases bank-conflict-free:
//  - coalesced phase (16 B lane stride): 8-lane groups cover all 32 banks
//  - window phase (64 B lane stride): XOR spreads the 2-bank aliasing apart
// No __syncthreads: each wave owns its LDS slice; DS ops are in-order per wave.
// ---------------------------------------------------------------------------
__global__ __launch_bounds__(256) void hblur_kernel(const float* __restrict__ x,
                                                    float* __restrict__ tmp,
                                                    GaussW gw)
{
    __shared__ __align__(16) float lds[4][1024];   // 16 KB / block

    const int t    = threadIdx.x;
    const int lane = t & 63;
    const int r    = t >> 6;                       // wave id, wave-uniform
    const long long row = (long long)blockIdx.x * 4 + r;
    const float* src = x + row * WW;
    char* Lrow = (char*)&lds[r][0];

    // byte-offset XOR swizzle (bits 4..6 ^= bits 7..9) — keeps 16B alignment
    #define SWZ(b) ((b) ^ ((((b) >> 7) & 7) << 4))

    // Phase 1: coalesced row load -> swizzled LDS
    #pragma unroll
    for (int g = 0; g < 4; g++) {
        const int c = g * 256 + lane * 4;          // float index, 16B aligned
        float4 v = *(const float4*)(src + c);
        *(float4*)(Lrow + SWZ(c * 4)) = v;
    }

    // Phase 2: windowed LDS reads + 816 FMAs (identical tap logic to R1).
    const int j0 = lane * 16;                      // outputs j0..j0+15
    float acc[16];
    #pragma unroll
    for (int d = 0; d < 16; d++) acc[d] = 0.f;

    #pragma unroll
    for (int i = 0; i < 18; i++) {
        const int col = j0 - 28 + i * 4;           // multiple of 4
        const bool in = ((unsigned)col < (unsigned)WW);  // fully in (<=1020) or out
        const int cc = in ? col : 0;
        float4 vv = *(const float4*)(Lrow + SWZ(cc * 4));
        if (!in) vv = make_float4(0.f, 0.f, 0.f, 0.f);
        const float vq[4] = {vv.x, vv.y, vv.z, vv.w};
        #pragma unroll
        for (int q = 0; q < 4; q++) {
            const int wi = i * 4 + q;              // window index: col j0-28+wi
            #pragma unroll
            for (int d = 0; d < 16; d++) {
                const int k = wi - 3 - d;          // compile-time tap index
                if (k >= 0 && k < KS)
                    acc[d] = fmaf(gw.w[k], vq[q], acc[d]);
            }
        }
    }

    // Phase 3: acc -> LDS (swizzled, strided writes: conflict-free per swizzle)
    #pragma unroll
    for (int g = 0; g < 4; g++) {
        const int c = j0 + g * 4;
        *(float4*)(Lrow + SWZ(c * 4)) =
            make_float4(acc[g*4], acc[g*4+1], acc[g*4+2], acc[g*4+3]);
    }

    // Phase 4: coalesced read-back -> coalesced global store
    float* dst = tmp + row * WW;
    #pragma unroll
    for (int g = 0; g < 4; g++) {
        const int c = g * 256 + lane * 4;
        float4 v = *(const float4*)(Lrow + SWZ(c * 4));
        *(float4*)(dst + c) = v;
    }
    #undef SWZ
}

// ---------------------------------------------------------------------------
// Vertical blur body, templated on INTERIOR so the 14/16 interior tiles get a
// completely branch-free loop of 66 unconditional float2 loads. Edge tiles use
// clamped-row loads with a zero-select — still unconditional loads.
// ---------------------------------------------------------------------------
template <bool INTERIOR>
__device__ __forceinline__ void vblur_accum(const float* __restrict__ tp,
                                            int r0, const GaussW& gw,
                                            float2 (&acc)[16])
{
    #pragma unroll
    for (int i = 0; i < 66; i++) {
        const int ri = r0 - RAD + i;
        float2 v;
        if (INTERIOR) {
            v = *(const float2*)(tp + (size_t)ri * WW);
        } else {
            const int ric = min(max(ri, 0), HH - 1);
            v = *(const float2*)(tp + (size_t)ric * WW);
            if ((unsigned)ri >= (unsigned)HH) v = make_float2(0.f, 0.f);
        }
        #pragma unroll
        for (int j = 0; j < 16; j++) {
            const int k = i - j;                  // compile-time tap index
            if (k >= 0 && k < KS) {
                const float wk = gw.w[k];
                acc[j].x = fmaf(wk, v.x, acc[j].x);
                acc[j].y = fmaf(wk, v.y, acc[j].y);
            }
        }
    }
}

// ---------------------------------------------------------------------------
// Vertical 51-tap blur + screen blend + clamp. Thread = 2 consecutive cols
// (float2) x 16 rows. Block-uniform interior/edge split hoists all bounds
// logic out of the load loop. tile_y inner so vertically-adjacent blocks
// share halo rows in L2.
// ---------------------------------------------------------------------------
__global__ __launch_bounds__(256) void vblend_kernel(const float* __restrict__ tmp,
                                                     const float* __restrict__ x,
                                                     float* __restrict__ out,
                                                     GaussW gw,
                                                     const float* __restrict__ amountp)
{
    const int t      = threadIdx.x;
    const int bid    = blockIdx.x;
    const int plane  = bid >> 7;            // 128 tiles per plane
    const int rem    = bid & 127;
    const int tile_x = rem >> 4;            // 8 col-tiles of 128
    const int tile_y = rem & 15;            // inner -> vertical L2 reuse
    const int c0     = tile_x * 128 + (t & 63) * 2;
    const int r0     = tile_y * 64 + (t >> 6) * 16;   // wave-uniform row group

    const float* tp = tmp + (size_t)plane * PLANE + c0;

    float2 acc[16];
    #pragma unroll
    for (int j = 0; j < 16; j++) acc[j] = make_float2(0.f, 0.f);

    // tile_y 1..14: rows r0-25 .. r0+40 all within [0,1024) -> branch-free.
    if (tile_y > 0 && tile_y < 15)
        vblur_accum<true>(tp, r0, gw, acc);
    else
        vblur_accum<false>(tp, r0, gw, acc);

    const float p = amountp[0];
    const float s = 1.2f * (0.4f / (1.f + expf(-p)));   // 1.2 * amount

    const float* xp = x   + (size_t)plane * PLANE + c0;
    float*       op = out + (size_t)plane * PLANE + c0;
    #pragma unroll
    for (int j = 0; j < 16; j++) {
        const float2 xv = *(const float2*)(xp + (size_t)(r0 + j) * WW);
        float2 res;
        res.x = 1.f - (1.f - xv.x) * (1.f - s * acc[j].x);
        res.y = 1.f - (1.f - xv.y) * (1.f - s * acc[j].y);
        res.x = fminf(fmaxf(res.x, 0.f), 1.f);
        res.y = fminf(fmaxf(res.y, 0.f), 1.f);
        *(float2*)(op + (size_t)(r0 + j) * WW) = res;
    }
}

// ---------------------------------------------------------------------------
extern "C" void kernel_launch(void* const* d_in, const int* in_sizes, int n_in,
                              void* d_out, int out_size, void* d_ws, size_t ws_size,
                              hipStream_t stream)
{
    const float* x       = (const float*)d_in[0];
    const float* amountp = (const float*)d_in[1];
    float* out = (float*)d_out;
    float* tmp = (float*)d_ws;

    // Gaussian weights (sigma=15, size 51), normalized — identical every call.
    GaussW gw;
    {
        double e[KS], sum = 0.0;
        for (int i = 0; i < KS; i++) {
            const double d = (double)(i - RAD);
            e[i] = exp(-d * d / (2.0 * 15.0 * 15.0));
            sum += e[i];
        }
        for (int i = 0; i < KS; i++) gw.w[i] = (float)(e[i] / sum);
    }

    const int total_planes = in_sizes[0] / PLANE;      // 24
    const size_t plane_bytes = (size_t)PLANE * sizeof(float);
    int P = (int)(ws_size / plane_bytes);
    if (P < 1) P = 1;
    if (P > total_planes) P = total_planes;

    for (int p0 = 0; p0 < total_planes; p0 += P) {
        const int pc = (total_planes - p0 < P) ? (total_planes - p0) : P;
        hblur_kernel<<<pc * 256, 256, 0, stream>>>(x + (size_t)p0 * PLANE, tmp, gw);
        vblend_kernel<<<pc * 128, 256, 0, stream>>>(tmp,
                                                    x + (size_t)p0 * PLANE,
                                                    out + (size_t)p0 * PLANE,
                                                    gw, amountp);
    }
}

// Round 4
// 236.456 us; speedup vs baseline: 1.2513x; 1.0200x over previous
//
#include <hip/hip_runtime.h>
#include <cmath>

#define HH 1024
#define WW 1024
#define KS 51
#define RAD 25
#define PLANE (HH * WW)

struct GaussW { float w[KS]; };

// ---------------------------------------------------------------------------
// Horizontal 51-tap blur, wave-per-row, LDS-staged (unchanged from R2: proven
// -47%, SQ_LDS_BANK_CONFLICT == 0).
// ---------------------------------------------------------------------------
__global__ __launch_bounds__(256) void hblur_kernel(const float* __restrict__ x,
                                                    float* __restrict__ tmp,
                                                    GaussW gw)
{
    __shared__ __align__(16) float lds[4][1024];   // 16 KB / block

    const int t    = threadIdx.x;
    const int lane = t & 63;
    const int r    = t >> 6;                       // wave id, wave-uniform
    const long long row = (long long)blockIdx.x * 4 + r;
    const float* src = x + row * WW;
    char* Lrow = (char*)&lds[r][0];

    // byte-offset XOR swizzle (bits 4..6 ^= bits 7..9) — keeps 16B alignment
    #define SWZ(b) ((b) ^ ((((b) >> 7) & 7) << 4))

    // Phase 1: coalesced row load -> swizzled LDS
    #pragma unroll
    for (int g = 0; g < 4; g++) {
        const int c = g * 256 + lane * 4;          // float index, 16B aligned
        float4 v = *(const float4*)(src + c);
        *(float4*)(Lrow + SWZ(c * 4)) = v;
    }

    // Phase 2: windowed LDS reads + 816 FMAs.
    const int j0 = lane * 16;                      // outputs j0..j0+15
    float acc[16];
    #pragma unroll
    for (int d = 0; d < 16; d++) acc[d] = 0.f;

    #pragma unroll
    for (int i = 0; i < 18; i++) {
        const int col = j0 - 28 + i * 4;           // multiple of 4
        const bool in = ((unsigned)col < (unsigned)WW);  // fully in (<=1020) or out
        const int cc = in ? col : 0;
        float4 vv = *(const float4*)(Lrow + SWZ(cc * 4));
        if (!in) vv = make_float4(0.f, 0.f, 0.f, 0.f);
        const float vq[4] = {vv.x, vv.y, vv.z, vv.w};
        #pragma unroll
        for (int q = 0; q < 4; q++) {
            const int wi = i * 4 + q;              // window index: col j0-28+wi
            #pragma unroll
            for (int d = 0; d < 16; d++) {
                const int k = wi - 3 - d;          // compile-time tap index
                if (k >= 0 && k < KS)
                    acc[d] = fmaf(gw.w[k], vq[q], acc[d]);
            }
        }
    }

    // Phase 3: acc -> LDS (swizzled)
    #pragma unroll
    for (int g = 0; g < 4; g++) {
        const int c = j0 + g * 4;
        *(float4*)(Lrow + SWZ(c * 4)) =
            make_float4(acc[g*4], acc[g*4+1], acc[g*4+2], acc[g*4+3]);
    }

    // Phase 4: coalesced read-back -> coalesced global store
    float* dst = tmp + row * WW;
    #pragma unroll
    for (int g = 0; g < 4; g++) {
        const int c = g * 256 + lane * 4;
        float4 v = *(const float4*)(Lrow + SWZ(c * 4));
        *(float4*)(dst + c) = v;
    }
    #undef SWZ
}

// ---------------------------------------------------------------------------
// Vertical 51-tap blur + screen blend + clamp, LDS-staged.
// R3 change: vblend showed the same "nothing saturated" profile (VALU 25%,
// HBM 36%): each thread re-read 66 rows from global per 16 outputs (4.1x
// L1-request redundancy, latency-exposed 512 B loads in the FMA chain).
// Now the block cooperatively stages its full tmp footprint (114 rows x
// 128 cols = 57 KB) into LDS with coalesced float4 loads (1.78x redundancy,
// 15 independent loads/thread -> deep MLP), zero-filling OOB rows at stage
// time so the accumulation body is uniform and branch-free for ALL tiles.
// 57 KB -> 2 blocks/CU: one block stages while the other computes.
// ---------------------------------------------------------------------------
__global__ __launch_bounds__(256) void vblend_kernel(const float* __restrict__ tmp,
                                                     const float* __restrict__ x,
                                                     float* __restrict__ out,
                                                     GaussW gw,
                                                     const float* __restrict__ amountp)
{
    __shared__ __align__(16) float s[114 * 128];   // 57 KB

    const int t      = threadIdx.x;
    const int bid    = blockIdx.x;
    const int plane  = bid >> 7;            // 128 tiles per plane
    const int rem    = bid & 127;
    const int tile_x = rem >> 4;            // 8 col-tiles of 128
    const int tile_y = rem & 15;            // inner -> vertical L2 reuse
    const int cb     = tile_x * 128;        // col base
    const int rb     = tile_y * 64;         // output rows rb..rb+63

    const float* tpl = tmp + (size_t)plane * PLANE;

    // Stage tmp rows rb-25 .. rb+88 (114) x cols cb..cb+127 into LDS.
    // 3648 float4 total; thread t does idx = it*256 + t (coalesced).
    #pragma unroll
    for (int it = 0; it < 15; it++) {
        const int idx = it * 256 + t;              // float4 index
        if (idx < 114 * 32) {
            const int row = idx >> 5;              // 0..113
            const int c4  = idx & 31;
            const int gr  = rb - 25 + row;
            const int grc = min(max(gr, 0), HH - 1);
            float4 v = *(const float4*)(tpl + (size_t)grc * WW + cb + c4 * 4);
            if ((unsigned)gr >= (unsigned)HH) v = make_float4(0.f, 0.f, 0.f, 0.f);
            *(float4*)(&s[row * 128 + c4 * 4]) = v;
        }
    }
    __syncthreads();

    const int lane = t & 63;
    const int wid  = t >> 6;                // wave-uniform
    const int lr0  = wid * 16;              // local output row group (0/16/32/48)
    const int c0l  = lane * 2;              // local col (float2)

    float2 acc[16];
    #pragma unroll
    for (int j = 0; j < 16; j++) acc[j] = make_float2(0.f, 0.f);

    // LDS rows lr0+i, i in [0,65] -> [0,113]: always in range, zeros baked in.
    #pragma unroll
    for (int i = 0; i < 66; i++) {
        const float2 v = *(const float2*)(&s[(lr0 + i) * 128 + c0l]);
        #pragma unroll
        for (int j = 0; j < 16; j++) {
            const int k = i - j;                  // compile-time tap index
            if (k >= 0 && k < KS) {
                const float wk = gw.w[k];
                acc[j].x = fmaf(wk, v.x, acc[j].x);
                acc[j].y = fmaf(wk, v.y, acc[j].y);
            }
        }
    }

    const float p = amountp[0];
    const float sc = 1.2f * (0.4f / (1.f + expf(-p)));   // 1.2 * amount

    const int r0 = rb + lr0;
    const int c0 = cb + c0l;
    const float* xp = x   + (size_t)plane * PLANE + c0;
    float*       op = out + (size_t)plane * PLANE + c0;
    #pragma unroll
    for (int j = 0; j < 16; j++) {
        const float2 xv = *(const float2*)(xp + (size_t)(r0 + j) * WW);
        float2 res;
        res.x = 1.f - (1.f - xv.x) * (1.f - sc * acc[j].x);
        res.y = 1.f - (1.f - xv.y) * (1.f - sc * acc[j].y);
        res.x = fminf(fmaxf(res.x, 0.f), 1.f);
        res.y = fminf(fmaxf(res.y, 0.f), 1.f);
        *(float2*)(op + (size_t)(r0 + j) * WW) = res;
    }
}

// ---------------------------------------------------------------------------
extern "C" void kernel_launch(void* const* d_in, const int* in_sizes, int n_in,
                              void* d_out, int out_size, void* d_ws, size_t ws_size,
                              hipStream_t stream)
{
    const float* x       = (const float*)d_in[0];
    const float* amountp = (const float*)d_in[1];
    float* out = (float*)d_out;
    float* tmp = (float*)d_ws;

    // Gaussian weights (sigma=15, size 51), normalized — identical every call.
    GaussW gw;
    {
        double e[KS], sum = 0.0;
        for (int i = 0; i < KS; i++) {
            const double d = (double)(i - RAD);
            e[i] = exp(-d * d / (2.0 * 15.0 * 15.0));
            sum += e[i];
        }
        for (int i = 0; i < KS; i++) gw.w[i] = (float)(e[i] / sum);
    }

    const int total_planes = in_sizes[0] / PLANE;      // 24
    const size_t plane_bytes = (size_t)PLANE * sizeof(float);
    int P = (int)(ws_size / plane_bytes);
    if (P < 1) P = 1;
    if (P > total_planes) P = total_planes;

    for (int p0 = 0; p0 < total_planes; p0 += P) {
        const int pc = (total_planes - p0 < P) ? (total_planes - p0) : P;
        hblur_kernel<<<pc * 256, 256, 0, stream>>>(x + (size_t)p0 * PLANE, tmp, gw);
        vblend_kernel<<<pc * 128, 256, 0, stream>>>(tmp,
                                                    x + (size_t)p0 * PLANE,
                                                    out + (size_t)p0 * PLANE,
                                                    gw, amountp);
    }
}